// Round 1
// baseline (978.162 us; speedup 1.0000x reference)
//
#include <hip/hip_runtime.h>

#define NPT   120000            // points per batch
#define NB    2                 // batches
#define NSEG  262144            // 512*512 pillars
#define NXg   512

// ---------------------------------------------------------------------------
// K1: per-point pillar id + segment count/sum (atomic scatter)
// ---------------------------------------------------------------------------
__global__ __launch_bounds__(256) void k_stats(const float* __restrict__ pts,
                                               unsigned int* __restrict__ cnt,
                                               float* __restrict__ sum,
                                               int* __restrict__ vids) {
    int tid = blockIdx.x * 256 + threadIdx.x;
    if (tid >= NB * NPT) return;
    const float* p = pts + (size_t)tid * 3;
    float x = p[0], y = p[1], z = p[2];
    // EXACT reference arithmetic: floor((x - lo)/vs), IEEE fp32 divide
    int xi = (int)floorf((x - (-51.2f)) / 0.2f);
    int yi = (int)floorf((y - (-51.2f)) / 0.2f);
    xi = min(max(xi, 0), 511);
    yi = min(max(yi, 0), 511);
    int b = (tid >= NPT) ? 1 : 0;
    int gvid = b * NSEG + (yi * NXg + xi);
    vids[tid] = gvid;
    atomicAdd(&cnt[gvid], 1u);
    atomicAdd(&sum[3 * (size_t)gvid + 0], x);
    atomicAdd(&sum[3 * (size_t)gvid + 1], y);
    atomicAdd(&sum[3 * (size_t)gvid + 2], z);
}

// ---------------------------------------------------------------------------
// K2: build 8-d features, PFN layer0 (Linear->BN->ReLU), scatter-max pooled0
// ---------------------------------------------------------------------------
__global__ __launch_bounds__(256) void k_pfn0(const float* __restrict__ pts,
                                              const unsigned int* __restrict__ cnt,
                                              const float* __restrict__ sum,
                                              const int* __restrict__ vids,
                                              const float* __restrict__ w0,
                                              const float* __restrict__ g0,
                                              const float* __restrict__ b0,
                                              const float* __restrict__ m0,
                                              const float* __restrict__ v0,
                                              float* __restrict__ h0buf,
                                              float* __restrict__ pooled0) {
    __shared__ float w0f[256];   // BN-folded weights [8][32]
    __shared__ float bias0[32];
    int t = threadIdx.x;
    {
        int c = t & 31;
        float al = g0[c] * rsqrtf(v0[c] + 1e-3f);
        w0f[t] = w0[t] * al;
        if (t < 32) bias0[t] = b0[t] - m0[t] * al;
    }
    __syncthreads();

    int tid = blockIdx.x * 256 + t;
    if (tid >= NB * NPT) return;

    const float* p = pts + (size_t)tid * 3;
    float x = p[0], y = p[1], z = p[2];
    int gvid = vids[tid];
    int vid = gvid & (NSEG - 1);
    int xi = vid & (NXg - 1), yi = vid >> 9;

    float c_ = (float)cnt[gvid];
    float inv = 1.0f / fmaxf(c_, 1.0f);
    float mx = sum[3 * (size_t)gvid + 0] * inv;
    float my = sum[3 * (size_t)gvid + 1] * inv;
    float mz = sum[3 * (size_t)gvid + 2] * inv;
    float cx = ((float)xi + 0.5f) * 0.2f + (-51.2f);
    float cy = ((float)yi + 0.5f) * 0.2f + (-51.2f);

    float f[8] = {x, y, z, x - mx, y - my, z - mz, x - cx, y - cy};

    float* hout = h0buf + (size_t)tid * 32;
    float* pb   = pooled0 + (size_t)gvid * 32;
    #pragma unroll
    for (int c = 0; c < 32; ++c) {
        float acc = bias0[c];
        #pragma unroll
        for (int k = 0; k < 8; ++k) acc += f[k] * w0f[k * 32 + c];
        acc = fmaxf(acc, 0.0f);                 // ReLU -> non-negative
        hout[c] = acc;
        // uint atomicMax valid for non-negative IEEE floats, buffer zero-init
        atomicMax((unsigned int*)&pb[c], __float_as_uint(acc));
    }
}

// ---------------------------------------------------------------------------
// K3: concat(h0, pooled0[vid]) -> PFN layer1 -> point_feats out + canvas max
//     4 points / block, 64 channels / point (one wave per point)
// ---------------------------------------------------------------------------
__global__ __launch_bounds__(256) void k_pfn1(const float* __restrict__ h0buf,
                                              const float* __restrict__ pooled0,
                                              const int* __restrict__ vids,
                                              const float* __restrict__ w1,
                                              const float* __restrict__ g1,
                                              const float* __restrict__ b1,
                                              const float* __restrict__ m1,
                                              const float* __restrict__ v1,
                                              float* __restrict__ out) {
    __shared__ float w1f[4096];  // BN-folded [64][64]
    __shared__ float bias1[64];
    __shared__ float xs[4][64];

    int t = threadIdx.x;
    #pragma unroll
    for (int i = 0; i < 16; ++i) {
        int idx = t + i * 256;
        int c = idx & 63;
        float al = g1[c] * rsqrtf(v1[c] + 1e-3f);
        w1f[idx] = w1[idx] * al;
    }
    if (t < 64) bias1[t] = b1[t] - m1[t] * (g1[t] * rsqrtf(v1[t] + 1e-3f));

    int pl = t >> 6, c = t & 63;
    int pt = blockIdx.x * 4 + pl;
    bool valid = (pt < NB * NPT);
    int gvid = 0;
    if (valid) {
        gvid = vids[pt];
        if (c < 32) xs[pl][c] = h0buf[(size_t)pt * 32 + c];
        else        xs[pl][c] = pooled0[(size_t)gvid * 32 + (c - 32)];
    }
    __syncthreads();
    if (!valid) return;

    float acc = bias1[c];
    #pragma unroll
    for (int k = 0; k < 64; ++k) acc += xs[pl][k] * w1f[k * 64 + c];
    acc = fmaxf(acc, 0.0f);

    int b = (pt >= NPT) ? 1 : 0;
    int li = pt - b * NPT;
    // output 1: point_feats [B, NPT, 64], after canvases
    out[(size_t)NB * 64 * NSEG + ((size_t)b * NPT + li) * 64 + c] = acc;
    // output 0: canvases [B, 64, 512, 512] -> idx = b*64*NSEG + c*NSEG + vid
    int vid = gvid & (NSEG - 1);
    atomicMax((unsigned int*)&out[((size_t)b * 64 + c) * NSEG + vid],
              __float_as_uint(acc));
}

// ---------------------------------------------------------------------------
extern "C" void kernel_launch(void* const* d_in, const int* in_sizes, int n_in,
                              void* d_out, int out_size, void* d_ws, size_t ws_size,
                              hipStream_t stream) {
    const float* pts = (const float*)d_in[0];
    const float* w0  = (const float*)d_in[1];
    const float* g0  = (const float*)d_in[2];
    const float* b0  = (const float*)d_in[3];
    const float* m0  = (const float*)d_in[4];
    const float* v0  = (const float*)d_in[5];
    const float* w1  = (const float*)d_in[6];
    const float* g1  = (const float*)d_in[7];
    const float* b1  = (const float*)d_in[8];
    const float* m1  = (const float*)d_in[9];
    const float* v1  = (const float*)d_in[10];
    float* out = (float*)d_out;

    // workspace layout
    char* ws = (char*)d_ws;
    size_t off = 0;
    unsigned int* cnt = (unsigned int*)(ws + off); off += (size_t)NB * NSEG * 4;
    float* sum        = (float*)(ws + off);        off += (size_t)NB * NSEG * 3 * 4;
    float* pooled0    = (float*)(ws + off);        off += (size_t)NB * NSEG * 32 * 4;
    float* h0buf      = (float*)(ws + off);        off += (size_t)NB * NPT * 32 * 4;
    int* vids         = (int*)(ws + off);          off += (size_t)NB * NPT * 4;

    // zero-init accumulators (harness poisons, does not re-poison between replays)
    hipMemsetAsync(cnt, 0, (size_t)NB * NSEG * 4, stream);
    hipMemsetAsync(sum, 0, (size_t)NB * NSEG * 3 * 4, stream);
    hipMemsetAsync(pooled0, 0, (size_t)NB * NSEG * 32 * 4, stream);
    hipMemsetAsync(out, 0, (size_t)NB * 64 * NSEG * 4, stream);   // canvas region

    int npts = NB * NPT;
    k_stats<<<(npts + 255) / 256, 256, 0, stream>>>(pts, cnt, sum, vids);
    k_pfn0<<<(npts + 255) / 256, 256, 0, stream>>>(pts, cnt, sum, vids,
                                                   w0, g0, b0, m0, v0,
                                                   h0buf, pooled0);
    k_pfn1<<<(npts + 3) / 4, 256, 0, stream>>>(h0buf, pooled0, vids,
                                               w1, g1, b1, m1, v1, out);
}

// Round 2
// 588.454 us; speedup vs baseline: 1.6623x; 1.6623x over previous
//
#include <hip/hip_runtime.h>

#define NPT   120000            // points per batch
#define NB    2                 // batches
#define NSEG  262144            // 512*512 pillars
#define NXg   512

// ---------------------------------------------------------------------------
// K1: per-point pillar id + segment count/sum (atomic scatter)
// ---------------------------------------------------------------------------
__global__ __launch_bounds__(256) void k_stats(const float* __restrict__ pts,
                                               unsigned int* __restrict__ cnt,
                                               float* __restrict__ sum,
                                               int* __restrict__ vids) {
    int tid = blockIdx.x * 256 + threadIdx.x;
    if (tid >= NB * NPT) return;
    const float* p = pts + (size_t)tid * 3;
    float x = p[0], y = p[1], z = p[2];
    // EXACT reference arithmetic: floor((x - lo)/vs), IEEE fp32 divide
    int xi = (int)floorf((x - (-51.2f)) / 0.2f);
    int yi = (int)floorf((y - (-51.2f)) / 0.2f);
    xi = min(max(xi, 0), 511);
    yi = min(max(yi, 0), 511);
    int b = (tid >= NPT) ? 1 : 0;
    int gvid = b * NSEG + (yi * NXg + xi);
    vids[tid] = gvid;
    atomicAdd(&cnt[gvid], 1u);
    atomicAdd(&sum[3 * (size_t)gvid + 0], x);
    atomicAdd(&sum[3 * (size_t)gvid + 1], y);
    atomicAdd(&sum[3 * (size_t)gvid + 2], z);
}

// ---------------------------------------------------------------------------
// K2: build 8-d features, PFN layer0 (Linear->BN->ReLU), scatter-max pooled0
// ---------------------------------------------------------------------------
__global__ __launch_bounds__(256) void k_pfn0(const float* __restrict__ pts,
                                              const unsigned int* __restrict__ cnt,
                                              const float* __restrict__ sum,
                                              const int* __restrict__ vids,
                                              const float* __restrict__ w0,
                                              const float* __restrict__ g0,
                                              const float* __restrict__ b0,
                                              const float* __restrict__ m0,
                                              const float* __restrict__ v0,
                                              float* __restrict__ h0buf,
                                              float* __restrict__ pooled0) {
    __shared__ float w0f[256];   // BN-folded weights [8][32]
    __shared__ float bias0[32];
    int t = threadIdx.x;
    {
        int c = t & 31;
        float al = g0[c] * rsqrtf(v0[c] + 1e-3f);
        w0f[t] = w0[t] * al;
        if (t < 32) bias0[t] = b0[t] - m0[t] * al;
    }
    __syncthreads();

    int tid = blockIdx.x * 256 + t;
    if (tid >= NB * NPT) return;

    const float* p = pts + (size_t)tid * 3;
    float x = p[0], y = p[1], z = p[2];
    int gvid = vids[tid];
    int vid = gvid & (NSEG - 1);
    int xi = vid & (NXg - 1), yi = vid >> 9;

    float c_ = (float)cnt[gvid];
    float inv = 1.0f / fmaxf(c_, 1.0f);
    float mx = sum[3 * (size_t)gvid + 0] * inv;
    float my = sum[3 * (size_t)gvid + 1] * inv;
    float mz = sum[3 * (size_t)gvid + 2] * inv;
    float cx = ((float)xi + 0.5f) * 0.2f + (-51.2f);
    float cy = ((float)yi + 0.5f) * 0.2f + (-51.2f);

    float f[8] = {x, y, z, x - mx, y - my, z - mz, x - cx, y - cy};

    float hv[32];
    #pragma unroll
    for (int c = 0; c < 32; ++c) {
        float acc = bias0[c];
        #pragma unroll
        for (int k = 0; k < 8; ++k) acc += f[k] * w0f[k * 32 + c];
        hv[c] = fmaxf(acc, 0.0f);               // ReLU -> non-negative
    }
    // vectorized h0 store
    float4* hout = (float4*)(h0buf + (size_t)tid * 32);
    #pragma unroll
    for (int q = 0; q < 8; ++q)
        hout[q] = make_float4(hv[4*q], hv[4*q+1], hv[4*q+2], hv[4*q+3]);
    // uint atomicMax valid for non-negative IEEE floats, buffer zero-init
    float* pb = pooled0 + (size_t)gvid * 32;
    #pragma unroll
    for (int c = 0; c < 32; ++c)
        atomicMax((unsigned int*)&pb[c], __float_as_uint(hv[c]));
}

// ---------------------------------------------------------------------------
// K3: concat(h0, pooled0[vid]) -> PFN layer1 -> point_feats out + vox max
//     4 points / block, 64 channels / point. vox is pillar-major [vid][64]
//     so the wave's 64 atomics hit 4 fully-dirty contiguous cache lines.
// ---------------------------------------------------------------------------
__global__ __launch_bounds__(256) void k_pfn1(const float* __restrict__ h0buf,
                                              const float* __restrict__ pooled0,
                                              const int* __restrict__ vids,
                                              const float* __restrict__ w1,
                                              const float* __restrict__ g1,
                                              const float* __restrict__ b1,
                                              const float* __restrict__ m1,
                                              const float* __restrict__ v1,
                                              float* __restrict__ ptfeat,
                                              float* __restrict__ vox,
                                              int batch) {
    __shared__ float w1f[4096];  // BN-folded [64][64]
    __shared__ float bias1[64];
    __shared__ float xs[4][64];

    int t = threadIdx.x;
    #pragma unroll
    for (int i = 0; i < 16; ++i) {
        int idx = t + i * 256;
        int c = idx & 63;
        float al = g1[c] * rsqrtf(v1[c] + 1e-3f);
        w1f[idx] = w1[idx] * al;
    }
    if (t < 64) bias1[t] = b1[t] - m1[t] * (g1[t] * rsqrtf(v1[t] + 1e-3f));

    int pl = t >> 6, c = t & 63;
    int li = blockIdx.x * 4 + pl;          // local point index within batch
    bool valid = (li < NPT);
    int pt = batch * NPT + li;
    int vid = 0;
    if (valid) {
        int gvid = vids[pt];
        vid = gvid & (NSEG - 1);
        if (c < 32) xs[pl][c] = h0buf[(size_t)pt * 32 + c];
        else        xs[pl][c] = pooled0[(size_t)gvid * 32 + (c - 32)];
    }
    __syncthreads();
    if (!valid) return;

    float acc = bias1[c];
    #pragma unroll
    for (int k = 0; k < 64; ++k) acc += xs[pl][k] * w1f[k * 64 + c];
    acc = fmaxf(acc, 0.0f);

    // output 1: point_feats [B, NPT, 64]
    ptfeat[((size_t)batch * NPT + li) * 64 + c] = acc;
    // pillar-major scatter-max: vox[vid][c] — dense 256B per pillar
    atomicMax((unsigned int*)&vox[(size_t)vid * 64 + c], __float_as_uint(acc));
}

// ---------------------------------------------------------------------------
// K4: transpose vox [NSEG][64] -> canvas [64][NSEG] (dense, coalesced)
// ---------------------------------------------------------------------------
__global__ __launch_bounds__(256) void k_transpose(const float* __restrict__ vox,
                                                   float* __restrict__ canvas) {
    __shared__ float tile[64][65];
    int t = threadIdx.x;
    size_t vid0 = (size_t)blockIdx.x * 64;
    const float* src = vox + vid0 * 64;
    #pragma unroll
    for (int i = 0; i < 16; ++i) {
        int idx = i * 256 + t;             // linear, coalesced read
        tile[idx & 63][idx >> 6] = src[idx];
    }
    __syncthreads();
    int p = t & 63;
    #pragma unroll
    for (int i = 0; i < 16; ++i) {
        int c = i * 4 + (t >> 6);
        canvas[(size_t)c * NSEG + vid0 + p] = tile[c][p];
    }
}

// ---------------------------------------------------------------------------
extern "C" void kernel_launch(void* const* d_in, const int* in_sizes, int n_in,
                              void* d_out, int out_size, void* d_ws, size_t ws_size,
                              hipStream_t stream) {
    const float* pts = (const float*)d_in[0];
    const float* w0  = (const float*)d_in[1];
    const float* g0  = (const float*)d_in[2];
    const float* b0  = (const float*)d_in[3];
    const float* m0  = (const float*)d_in[4];
    const float* v0  = (const float*)d_in[5];
    const float* w1  = (const float*)d_in[6];
    const float* g1  = (const float*)d_in[7];
    const float* b1  = (const float*)d_in[8];
    const float* m1  = (const float*)d_in[9];
    const float* v1  = (const float*)d_in[10];
    float* out = (float*)d_out;
    float* ptfeat = out + (size_t)NB * 64 * NSEG;   // point_feats after canvases

    // workspace layout (~174 MB peak)
    char* ws = (char*)d_ws;
    size_t off = 0;
    unsigned int* cnt = (unsigned int*)(ws + off); off += (size_t)NB * NSEG * 4;
    float* sum        = (float*)(ws + off);        off += (size_t)NB * NSEG * 3 * 4;
    int* vids         = (int*)(ws + off);          off += (size_t)NB * NPT * 4;
    float* h0buf      = (float*)(ws + off);        off += (size_t)NB * NPT * 32 * 4;
    float* pooled0    = (float*)(ws + off);        off += (size_t)NB * NSEG * 32 * 4;
    float* vox        = (float*)(ws + off);        off += (size_t)NSEG * 64 * 4;

    hipMemsetAsync(cnt, 0, (size_t)NB * NSEG * 4, stream);
    hipMemsetAsync(sum, 0, (size_t)NB * NSEG * 3 * 4, stream);
    hipMemsetAsync(pooled0, 0, (size_t)NB * NSEG * 32 * 4, stream);

    int npts = NB * NPT;
    k_stats<<<(npts + 255) / 256, 256, 0, stream>>>(pts, cnt, sum, vids);
    k_pfn0<<<(npts + 255) / 256, 256, 0, stream>>>(pts, cnt, sum, vids,
                                                   w0, g0, b0, m0, v0,
                                                   h0buf, pooled0);
    for (int b = 0; b < NB; ++b) {
        hipMemsetAsync(vox, 0, (size_t)NSEG * 64 * 4, stream);
        k_pfn1<<<(NPT + 3) / 4, 256, 0, stream>>>(h0buf, pooled0, vids,
                                                  w1, g1, b1, m1, v1,
                                                  ptfeat, vox, b);
        k_transpose<<<NSEG / 64, 256, 0, stream>>>(vox,
                                                   out + (size_t)b * 64 * NSEG);
    }
}

// Round 3
// 515.802 us; speedup vs baseline: 1.8964x; 1.1409x over previous
//
#include <hip/hip_runtime.h>

#define NPT   120000            // points per batch
#define NB    2                 // batches
#define NSEG  262144            // 512*512 pillars
#define NXg   512
#define NSEGT (NB * NSEG)       // 524288 total segments

// ---------------------------------------------------------------------------
// K1: per-point pillar id + segment count/sum; rank = arrival order in pillar
// ---------------------------------------------------------------------------
__global__ __launch_bounds__(256) void k_stats(const float* __restrict__ pts,
                                               unsigned int* __restrict__ cnt,
                                               float* __restrict__ sum,
                                               int* __restrict__ vids,
                                               unsigned int* __restrict__ rank) {
    int tid = blockIdx.x * 256 + threadIdx.x;
    if (tid >= NB * NPT) return;
    const float* p = pts + (size_t)tid * 3;
    float x = p[0], y = p[1], z = p[2];
    // EXACT reference arithmetic: floor((x - lo)/vs), IEEE fp32 divide
    int xi = (int)floorf((x - (-51.2f)) / 0.2f);
    int yi = (int)floorf((y - (-51.2f)) / 0.2f);
    xi = min(max(xi, 0), 511);
    yi = min(max(yi, 0), 511);
    int b = (tid >= NPT) ? 1 : 0;
    int gvid = b * NSEG + (yi * NXg + xi);
    vids[tid] = gvid;
    rank[tid] = atomicAdd(&cnt[gvid], 1u);
    atomicAdd(&sum[3 * (size_t)gvid + 0], x);
    atomicAdd(&sum[3 * (size_t)gvid + 1], y);
    atomicAdd(&sum[3 * (size_t)gvid + 2], z);
}

// ---------------------------------------------------------------------------
// Exclusive prefix scan of cnt[524288] -> offs.  1024 elems/block, 512 blocks.
// ---------------------------------------------------------------------------
__global__ __launch_bounds__(256) void k_scan1(const unsigned int* __restrict__ cnt,
                                               unsigned int* __restrict__ offs,
                                               unsigned int* __restrict__ bsum) {
    __shared__ unsigned int s[256];
    int t = threadIdx.x;
    size_t base = (size_t)blockIdx.x * 1024 + t * 4;
    uint4 c4 = *(const uint4*)(cnt + base);
    unsigned int tsum = c4.x + c4.y + c4.z + c4.w;
    s[t] = tsum;
    __syncthreads();
    for (int o = 1; o < 256; o <<= 1) {
        unsigned int v = (t >= o) ? s[t - o] : 0u;
        __syncthreads();
        s[t] += v;
        __syncthreads();
    }
    unsigned int pre = s[t] - tsum;          // exclusive within block
    if (t == 255) bsum[blockIdx.x] = s[255];
    uint4 o4;
    o4.x = pre; o4.y = pre + c4.x; o4.z = o4.y + c4.y; o4.w = o4.z + c4.z;
    *(uint4*)(offs + base) = o4;
}

__global__ __launch_bounds__(256) void k_scan2(unsigned int* __restrict__ bsum) {
    __shared__ unsigned int s[256];
    int t = threadIdx.x;
    unsigned int a = bsum[2 * t], b = bsum[2 * t + 1];
    unsigned int ts = a + b;
    s[t] = ts;
    __syncthreads();
    for (int o = 1; o < 256; o <<= 1) {
        unsigned int v = (t >= o) ? s[t - o] : 0u;
        __syncthreads();
        s[t] += v;
        __syncthreads();
    }
    unsigned int pre = s[t] - ts;
    bsum[2 * t] = pre;
    bsum[2 * t + 1] = pre + a;
}

__global__ __launch_bounds__(256) void k_scan3(unsigned int* __restrict__ offs,
                                               const unsigned int* __restrict__ bsum) {
    size_t base = (size_t)blockIdx.x * 1024 + threadIdx.x * 4;
    unsigned int add = bsum[blockIdx.x];
    uint4 o4 = *(uint4*)(offs + base);
    o4.x += add; o4.y += add; o4.z += add; o4.w += add;
    *(uint4*)(offs + base) = o4;
}

// ---------------------------------------------------------------------------
// K2: 8-d features -> PFN layer0 -> h0 written at pillar-sorted position.
//     No atomics: pos = offs[gvid] + rank.
// ---------------------------------------------------------------------------
__global__ __launch_bounds__(256) void k_pfn0(const float* __restrict__ pts,
                                              const unsigned int* __restrict__ cnt,
                                              const float* __restrict__ sum,
                                              const int* __restrict__ vids,
                                              const unsigned int* __restrict__ rank,
                                              const unsigned int* __restrict__ offs,
                                              const float* __restrict__ w0,
                                              const float* __restrict__ g0,
                                              const float* __restrict__ b0,
                                              const float* __restrict__ m0,
                                              const float* __restrict__ v0,
                                              float* __restrict__ h0sorted,
                                              int* __restrict__ ptofpos) {
    __shared__ float w0f[256];   // BN-folded weights [8][32]
    __shared__ float bias0[32];
    int t = threadIdx.x;
    {
        int c = t & 31;
        float al = g0[c] * rsqrtf(v0[c] + 1e-3f);
        w0f[t] = w0[t] * al;
        if (t < 32) bias0[t] = b0[t] - m0[t] * al;
    }
    __syncthreads();

    int tid = blockIdx.x * 256 + t;
    if (tid >= NB * NPT) return;

    const float* p = pts + (size_t)tid * 3;
    float x = p[0], y = p[1], z = p[2];
    int gvid = vids[tid];
    int vid = gvid & (NSEG - 1);
    int xi = vid & (NXg - 1), yi = vid >> 9;

    float c_ = (float)cnt[gvid];
    float inv = 1.0f / fmaxf(c_, 1.0f);
    float mx = sum[3 * (size_t)gvid + 0] * inv;
    float my = sum[3 * (size_t)gvid + 1] * inv;
    float mz = sum[3 * (size_t)gvid + 2] * inv;
    float cx = ((float)xi + 0.5f) * 0.2f + (-51.2f);
    float cy = ((float)yi + 0.5f) * 0.2f + (-51.2f);

    float f[8] = {x, y, z, x - mx, y - my, z - mz, x - cx, y - cy};

    float hv[32];
    #pragma unroll
    for (int c = 0; c < 32; ++c) {
        float acc = bias0[c];
        #pragma unroll
        for (int k = 0; k < 8; ++k) acc += f[k] * w0f[k * 32 + c];
        hv[c] = fmaxf(acc, 0.0f);               // ReLU -> non-negative
    }
    unsigned int pos = offs[gvid] + rank[tid];
    float4* hout = (float4*)(h0sorted + (size_t)pos * 32);
    #pragma unroll
    for (int q = 0; q < 8; ++q)
        hout[q] = make_float4(hv[4*q], hv[4*q+1], hv[4*q+2], hv[4*q+3]);
    ptofpos[pos] = tid;
}

// ---------------------------------------------------------------------------
// K3: one wave per pillar. Gathers the pillar's sorted points, computes
//     pooled0 in-register, 64x64 GEMV via shfl-broadcast + LDS weights.
//     Writes point_feats (coalesced 256B/point) and dense vox row.
//     ZERO atomics.  Block = 1024 threads = 16 pillars.
// ---------------------------------------------------------------------------
__global__ __launch_bounds__(1024) void k_pfn1(const float* __restrict__ h0sorted,
                                               const int* __restrict__ ptofpos,
                                               const unsigned int* __restrict__ offs,
                                               const unsigned int* __restrict__ cnt,
                                               const float* __restrict__ w1,
                                               const float* __restrict__ g1,
                                               const float* __restrict__ b1,
                                               const float* __restrict__ m1,
                                               const float* __restrict__ v1,
                                               float* __restrict__ ptfeat,
                                               float* __restrict__ vox,
                                               int batch) {
    __shared__ float w1f[4096];  // BN-folded [64][64]
    __shared__ float bias1[64];
    int t = threadIdx.x;
    #pragma unroll
    for (int i = 0; i < 4; ++i) {
        int idx = t + i * 1024;
        int c = idx & 63;
        float al = g1[c] * rsqrtf(v1[c] + 1e-3f);
        w1f[idx] = w1[idx] * al;
    }
    if (t < 64) bias1[t] = b1[t] - m1[t] * (g1[t] * rsqrtf(v1[t] + 1e-3f));
    __syncthreads();

    int c = t & 63;            // output channel (lane)
    int k = c & 31;            // input-half channel this lane reads
    int vid = blockIdx.x * 16 + (t >> 6);
    int gvid = batch * NSEG + vid;
    unsigned int off = offs[gvid];
    unsigned int n   = cnt[gvid];

    float vmax = 0.0f;
    if (n) {
        // pooled0[k] = max over pillar points of h0[k]  (lane-resident)
        float pool = 0.0f;
        for (unsigned int i = 0; i < n; ++i)
            pool = fmaxf(pool, h0sorted[(size_t)(off + i) * 32 + k]);
        // pooled half of the GEMV + bias, shared by all points in the pillar
        float accP = bias1[c];
        #pragma unroll
        for (int kk = 0; kk < 32; ++kk)
            accP += __shfl(pool, kk) * w1f[(32 + kk) * 64 + c];
        for (unsigned int i = 0; i < n; ++i) {
            float h0v = h0sorted[(size_t)(off + i) * 32 + k];
            float acc = accP;
            #pragma unroll
            for (int kk = 0; kk < 32; ++kk)
                acc += __shfl(h0v, kk) * w1f[kk * 64 + c];
            acc = fmaxf(acc, 0.0f);
            int orig = ptofpos[off + i];     // global point id = b*NPT + li
            ptfeat[(size_t)orig * 64 + c] = acc;
            vmax = fmaxf(vmax, acc);
        }
    }
    vox[(size_t)vid * 64 + c] = vmax;        // zeros for empty pillars
}

// ---------------------------------------------------------------------------
// K4: transpose vox [NSEG][64] -> canvas [64][NSEG] (dense, coalesced)
// ---------------------------------------------------------------------------
__global__ __launch_bounds__(256) void k_transpose(const float* __restrict__ vox,
                                                   float* __restrict__ canvas) {
    __shared__ float tile[64][65];
    int t = threadIdx.x;
    size_t vid0 = (size_t)blockIdx.x * 64;
    const float* src = vox + vid0 * 64;
    #pragma unroll
    for (int i = 0; i < 16; ++i) {
        int idx = i * 256 + t;             // linear, coalesced read
        tile[idx & 63][idx >> 6] = src[idx];
    }
    __syncthreads();
    int p = t & 63;
    #pragma unroll
    for (int i = 0; i < 16; ++i) {
        int c = i * 4 + (t >> 6);
        canvas[(size_t)c * NSEG + vid0 + p] = tile[c][p];
    }
}

// ---------------------------------------------------------------------------
extern "C" void kernel_launch(void* const* d_in, const int* in_sizes, int n_in,
                              void* d_out, int out_size, void* d_ws, size_t ws_size,
                              hipStream_t stream) {
    const float* pts = (const float*)d_in[0];
    const float* w0  = (const float*)d_in[1];
    const float* g0  = (const float*)d_in[2];
    const float* b0  = (const float*)d_in[3];
    const float* m0  = (const float*)d_in[4];
    const float* v0  = (const float*)d_in[5];
    const float* w1  = (const float*)d_in[6];
    const float* g1  = (const float*)d_in[7];
    const float* b1  = (const float*)d_in[8];
    const float* m1  = (const float*)d_in[9];
    const float* v1  = (const float*)d_in[10];
    float* out = (float*)d_out;
    float* ptfeat = out + (size_t)NB * 64 * NSEG;   // point_feats after canvases

    // workspace layout (~111 MB peak)
    char* ws = (char*)d_ws;
    size_t off = 0;
    unsigned int* cnt  = (unsigned int*)(ws + off); off += (size_t)NSEGT * 4;        // 2.1 MB
    float* sum         = (float*)(ws + off);        off += (size_t)NSEGT * 3 * 4;    // 6.3 MB
    int* vids          = (int*)(ws + off);          off += (size_t)NB * NPT * 4;     // 1 MB
    unsigned int* rank = (unsigned int*)(ws + off); off += (size_t)NB * NPT * 4;     // 1 MB
    unsigned int* offs = (unsigned int*)(ws + off); off += (size_t)NSEGT * 4;        // 2.1 MB
    int* ptofpos       = (int*)(ws + off);          off += (size_t)NB * NPT * 4;     // 1 MB
    float* h0sorted    = (float*)(ws + off);        off += (size_t)NB * NPT * 32 * 4;// 31 MB
    unsigned int* bsum = (unsigned int*)(ws + off); off += 512 * 4;
    off = (off + 255) & ~(size_t)255;
    float* vox         = (float*)(ws + off);        off += (size_t)NSEG * 64 * 4;    // 67 MB

    hipMemsetAsync(cnt, 0, (size_t)NSEGT * 4, stream);
    hipMemsetAsync(sum, 0, (size_t)NSEGT * 3 * 4, stream);

    int npts = NB * NPT;
    k_stats<<<(npts + 255) / 256, 256, 0, stream>>>(pts, cnt, sum, vids, rank);
    k_scan1<<<NSEGT / 1024, 256, 0, stream>>>(cnt, offs, bsum);
    k_scan2<<<1, 256, 0, stream>>>(bsum);
    k_scan3<<<NSEGT / 1024, 256, 0, stream>>>(offs, bsum);
    k_pfn0<<<(npts + 255) / 256, 256, 0, stream>>>(pts, cnt, sum, vids, rank, offs,
                                                   w0, g0, b0, m0, v0,
                                                   h0sorted, ptofpos);
    for (int b = 0; b < NB; ++b) {
        k_pfn1<<<NSEG / 16, 1024, 0, stream>>>(h0sorted, ptofpos, offs, cnt,
                                               w1, g1, b1, m1, v1,
                                               ptfeat, vox, b);
        k_transpose<<<NSEG / 64, 256, 0, stream>>>(vox,
                                                   out + (size_t)b * 64 * NSEG);
    }
}

// Round 4
// 225.227 us; speedup vs baseline: 4.3430x; 2.2901x over previous
//
#include <hip/hip_runtime.h>

#define NPT   120000            // points per batch
#define NB    2                 // batches
#define NSEG  262144            // 512*512 pillars
#define NXg   512
#define NSEGT (NB * NSEG)       // 524288 total segments

// ---------------------------------------------------------------------------
// K1: per-point pillar id + segment count/sum; rank = arrival order in pillar
// ---------------------------------------------------------------------------
__global__ __launch_bounds__(256) void k_stats(const float* __restrict__ pts,
                                               unsigned int* __restrict__ cnt,
                                               float* __restrict__ sum,
                                               int* __restrict__ vids,
                                               unsigned int* __restrict__ rank) {
    int tid = blockIdx.x * 256 + threadIdx.x;
    if (tid >= NB * NPT) return;
    const float* p = pts + (size_t)tid * 3;
    float x = p[0], y = p[1], z = p[2];
    // EXACT reference arithmetic: floor((x - lo)/vs), IEEE fp32 divide
    int xi = (int)floorf((x - (-51.2f)) / 0.2f);
    int yi = (int)floorf((y - (-51.2f)) / 0.2f);
    xi = min(max(xi, 0), 511);
    yi = min(max(yi, 0), 511);
    int b = (tid >= NPT) ? 1 : 0;
    int gvid = b * NSEG + (yi * NXg + xi);
    vids[tid] = gvid;
    rank[tid] = atomicAdd(&cnt[gvid], 1u);
    atomicAdd(&sum[3 * (size_t)gvid + 0], x);
    atomicAdd(&sum[3 * (size_t)gvid + 1], y);
    atomicAdd(&sum[3 * (size_t)gvid + 2], z);
}

// ---------------------------------------------------------------------------
// Exclusive prefix scan of cnt[524288] -> offs.  1024 elems/block, 512 blocks.
// ---------------------------------------------------------------------------
__global__ __launch_bounds__(256) void k_scan1(const unsigned int* __restrict__ cnt,
                                               unsigned int* __restrict__ offs,
                                               unsigned int* __restrict__ bsum) {
    __shared__ unsigned int s[256];
    int t = threadIdx.x;
    size_t base = (size_t)blockIdx.x * 1024 + t * 4;
    uint4 c4 = *(const uint4*)(cnt + base);
    unsigned int tsum = c4.x + c4.y + c4.z + c4.w;
    s[t] = tsum;
    __syncthreads();
    for (int o = 1; o < 256; o <<= 1) {
        unsigned int v = (t >= o) ? s[t - o] : 0u;
        __syncthreads();
        s[t] += v;
        __syncthreads();
    }
    unsigned int pre = s[t] - tsum;          // exclusive within block
    if (t == 255) bsum[blockIdx.x] = s[255];
    uint4 o4;
    o4.x = pre; o4.y = pre + c4.x; o4.z = o4.y + c4.y; o4.w = o4.z + c4.z;
    *(uint4*)(offs + base) = o4;
}

__global__ __launch_bounds__(256) void k_scan2(unsigned int* __restrict__ bsum) {
    __shared__ unsigned int s[256];
    int t = threadIdx.x;
    unsigned int a = bsum[2 * t], b = bsum[2 * t + 1];
    unsigned int ts = a + b;
    s[t] = ts;
    __syncthreads();
    for (int o = 1; o < 256; o <<= 1) {
        unsigned int v = (t >= o) ? s[t - o] : 0u;
        __syncthreads();
        s[t] += v;
        __syncthreads();
    }
    unsigned int pre = s[t] - ts;
    bsum[2 * t] = pre;
    bsum[2 * t + 1] = pre + a;
}

__global__ __launch_bounds__(256) void k_scan3(unsigned int* __restrict__ offs,
                                               const unsigned int* __restrict__ bsum) {
    size_t base = (size_t)blockIdx.x * 1024 + threadIdx.x * 4;
    unsigned int add = bsum[blockIdx.x];
    uint4 o4 = *(uint4*)(offs + base);
    o4.x += add; o4.y += add; o4.z += add; o4.w += add;
    *(uint4*)(offs + base) = o4;
}

// ---------------------------------------------------------------------------
// K2: 8-d features -> PFN layer0 -> h0 written at pillar-sorted position.
//     No atomics: pos = offs[gvid] + rank.
// ---------------------------------------------------------------------------
__global__ __launch_bounds__(256) void k_pfn0(const float* __restrict__ pts,
                                              const unsigned int* __restrict__ cnt,
                                              const float* __restrict__ sum,
                                              const int* __restrict__ vids,
                                              const unsigned int* __restrict__ rank,
                                              const unsigned int* __restrict__ offs,
                                              const float* __restrict__ w0,
                                              const float* __restrict__ g0,
                                              const float* __restrict__ b0,
                                              const float* __restrict__ m0,
                                              const float* __restrict__ v0,
                                              float* __restrict__ h0sorted,
                                              int* __restrict__ ptofpos) {
    __shared__ float w0f[256];   // BN-folded weights [8][32]
    __shared__ float bias0[32];
    int t = threadIdx.x;
    {
        int c = t & 31;
        float al = g0[c] * rsqrtf(v0[c] + 1e-3f);
        w0f[t] = w0[t] * al;
        if (t < 32) bias0[t] = b0[t] - m0[t] * al;
    }
    __syncthreads();

    int tid = blockIdx.x * 256 + t;
    if (tid >= NB * NPT) return;

    const float* p = pts + (size_t)tid * 3;
    float x = p[0], y = p[1], z = p[2];
    int gvid = vids[tid];
    int vid = gvid & (NSEG - 1);
    int xi = vid & (NXg - 1), yi = vid >> 9;

    float c_ = (float)cnt[gvid];
    float inv = 1.0f / fmaxf(c_, 1.0f);
    float mx = sum[3 * (size_t)gvid + 0] * inv;
    float my = sum[3 * (size_t)gvid + 1] * inv;
    float mz = sum[3 * (size_t)gvid + 2] * inv;
    float cx = ((float)xi + 0.5f) * 0.2f + (-51.2f);
    float cy = ((float)yi + 0.5f) * 0.2f + (-51.2f);

    float f[8] = {x, y, z, x - mx, y - my, z - mz, x - cx, y - cy};

    float hv[32];
    #pragma unroll
    for (int c = 0; c < 32; ++c) {
        float acc = bias0[c];
        #pragma unroll
        for (int k = 0; k < 8; ++k) acc += f[k] * w0f[k * 32 + c];
        hv[c] = fmaxf(acc, 0.0f);               // ReLU -> non-negative
    }
    unsigned int pos = offs[gvid] + rank[tid];
    float4* hout = (float4*)(h0sorted + (size_t)pos * 32);
    #pragma unroll
    for (int q = 0; q < 8; ++q)
        hout[q] = make_float4(hv[4*q], hv[4*q+1], hv[4*q+2], hv[4*q+3]);
    ptofpos[pos] = tid;
}

// ---------------------------------------------------------------------------
// K3 (fused): 64 pillars per 512-thread block.
//   Pass A: pooled0[64][32] per-pillar max in LDS (no atomics, no shfl)
//   Pass B: per-point 64x64 GEMV (broadcast float4 h0 loads + LDS weights),
//           ptfeat write (256B/point contiguous), per-pillar vmax -> voxl
//   Pass C: transposed coalesced write of the 64x64 tile into the canvas
// ---------------------------------------------------------------------------
__global__ __launch_bounds__(512) void k_pfn1(const float* __restrict__ h0sorted,
                                              const int* __restrict__ ptofpos,
                                              const unsigned int* __restrict__ offs,
                                              const unsigned int* __restrict__ cnt,
                                              const float* __restrict__ w1,
                                              const float* __restrict__ g1,
                                              const float* __restrict__ b1,
                                              const float* __restrict__ m1,
                                              const float* __restrict__ v1,
                                              float* __restrict__ ptfeat,
                                              float* __restrict__ canvas) {
    __shared__ float w1f[4096];      // BN-folded [64in][64out]
    __shared__ float bias1[64];
    __shared__ float pooled[64][32]; // per-pillar pooled0
    __shared__ float voxl[64][65];   // per-pillar output max (padded)

    int t = threadIdx.x;
    #pragma unroll
    for (int i = 0; i < 8; ++i) {
        int idx = t + i * 512;
        int c = idx & 63;
        float al = g1[c] * rsqrtf(v1[c] + 1e-3f);
        w1f[idx] = w1[idx] * al;
    }
    if (t < 64) bias1[t] = b1[t] - m1[t] * (g1[t] * rsqrtf(v1[t] + 1e-3f));
    #pragma unroll
    for (int i = 0; i < 4; ++i) ((float*)pooled)[t + i * 512] = 0.0f;
    __syncthreads();

    int batch = blockIdx.x >> 12;             // 4096 blocks per batch
    int vid0 = (blockIdx.x & 4095) * 64;
    int gvid0 = batch * NSEG + vid0;

    // ---- Pass A: pooled max, 16 groups x 32 lanes, 4 pillars each ----
    {
        int g = t >> 5, k = t & 31;
        #pragma unroll
        for (int j = 0; j < 4; ++j) {
            int vloc = g * 4 + j;
            unsigned int off = offs[gvid0 + vloc];
            unsigned int n   = cnt[gvid0 + vloc];
            float pool = 0.0f;
            for (unsigned int i = 0; i < n; ++i)
                pool = fmaxf(pool, h0sorted[(size_t)(off + i) * 32 + k]);
            pooled[vloc][k] = pool;
        }
    }
    __syncthreads();

    // ---- Pass B: per-point GEMV, 8 groups x 64 lanes, 8 pillars each ----
    {
        int g = t >> 6, c = t & 63;
        for (int j = 0; j < 8; ++j) {
            int vloc = g * 8 + j;
            unsigned int off = offs[gvid0 + vloc];
            unsigned int n   = cnt[gvid0 + vloc];
            float vmax = 0.0f;
            if (n) {
                float accP = bias1[c];       // pooled half, shared in pillar
                #pragma unroll
                for (int kk = 0; kk < 32; ++kk)
                    accP += pooled[vloc][kk] * w1f[(32 + kk) * 64 + c];
                for (unsigned int i = 0; i < n; ++i) {
                    size_t pos = off + i;
                    const float4* h4 = (const float4*)(h0sorted + pos * 32);
                    float acc = accP;
                    #pragma unroll
                    for (int q = 0; q < 8; ++q) {
                        float4 v = h4[q];
                        acc += v.x * w1f[(4 * q + 0) * 64 + c];
                        acc += v.y * w1f[(4 * q + 1) * 64 + c];
                        acc += v.z * w1f[(4 * q + 2) * 64 + c];
                        acc += v.w * w1f[(4 * q + 3) * 64 + c];
                    }
                    acc = fmaxf(acc, 0.0f);
                    int orig = ptofpos[pos];           // global point id
                    ptfeat[(size_t)orig * 64 + c] = acc;
                    vmax = fmaxf(vmax, acc);
                }
            }
            voxl[vloc][c] = vmax;
        }
    }
    __syncthreads();

    // ---- Pass C: transposed write voxl -> canvas [64][NSEG] ----
    {
        float* cv = canvas + (size_t)batch * 64 * NSEG + vid0;
        int p = t & 63;
        #pragma unroll
        for (int i = 0; i < 8; ++i) {
            int c = i * 8 + (t >> 6);
            cv[(size_t)c * NSEG + p] = voxl[p][c];
        }
    }
}

// ---------------------------------------------------------------------------
extern "C" void kernel_launch(void* const* d_in, const int* in_sizes, int n_in,
                              void* d_out, int out_size, void* d_ws, size_t ws_size,
                              hipStream_t stream) {
    const float* pts = (const float*)d_in[0];
    const float* w0  = (const float*)d_in[1];
    const float* g0  = (const float*)d_in[2];
    const float* b0  = (const float*)d_in[3];
    const float* m0  = (const float*)d_in[4];
    const float* v0  = (const float*)d_in[5];
    const float* w1  = (const float*)d_in[6];
    const float* g1  = (const float*)d_in[7];
    const float* b1  = (const float*)d_in[8];
    const float* m1  = (const float*)d_in[9];
    const float* v1  = (const float*)d_in[10];
    float* out = (float*)d_out;
    float* ptfeat = out + (size_t)NB * 64 * NSEG;   // point_feats after canvases

    // workspace layout (~45 MB peak)
    char* ws = (char*)d_ws;
    size_t off = 0;
    unsigned int* cnt  = (unsigned int*)(ws + off); off += (size_t)NSEGT * 4;
    float* sum         = (float*)(ws + off);        off += (size_t)NSEGT * 3 * 4;
    int* vids          = (int*)(ws + off);          off += (size_t)NB * NPT * 4;
    unsigned int* rank = (unsigned int*)(ws + off); off += (size_t)NB * NPT * 4;
    unsigned int* offs = (unsigned int*)(ws + off); off += (size_t)NSEGT * 4;
    int* ptofpos       = (int*)(ws + off);          off += (size_t)NB * NPT * 4;
    float* h0sorted    = (float*)(ws + off);        off += (size_t)NB * NPT * 32 * 4;
    unsigned int* bsum = (unsigned int*)(ws + off); off += 512 * 4;

    hipMemsetAsync(cnt, 0, (size_t)NSEGT * 4, stream);
    hipMemsetAsync(sum, 0, (size_t)NSEGT * 3 * 4, stream);

    int npts = NB * NPT;
    k_stats<<<(npts + 255) / 256, 256, 0, stream>>>(pts, cnt, sum, vids, rank);
    k_scan1<<<NSEGT / 1024, 256, 0, stream>>>(cnt, offs, bsum);
    k_scan2<<<1, 256, 0, stream>>>(bsum);
    k_scan3<<<NSEGT / 1024, 256, 0, stream>>>(offs, bsum);
    k_pfn0<<<(npts + 255) / 256, 256, 0, stream>>>(pts, cnt, sum, vids, rank, offs,
                                                   w0, g0, b0, m0, v0,
                                                   h0sorted, ptofpos);
    k_pfn1<<<NB * 4096, 512, 0, stream>>>(h0sorted, ptofpos, offs, cnt,
                                          w1, g1, b1, m1, v1, ptfeat, out);
}

// Round 5
// 129.434 us; speedup vs baseline: 7.5572x; 1.7401x over previous
//
#include <hip/hip_runtime.h>

#define NPT   120000            // points per batch
#define NB    2                 // batches
#define NSEG  262144            // 512*512 pillars
#define NXg   512
#define NSEGT (NB * NSEG)       // 524288 total segments

typedef __attribute__((ext_vector_type(8))) short  bf16x8;
typedef __attribute__((ext_vector_type(4))) float  f32x4;

__device__ __forceinline__ unsigned short f2bf(float f) {
    unsigned u = __float_as_uint(f);
    return (unsigned short)((u + 0x7FFFu + ((u >> 16) & 1u)) >> 16);   // RNE
}

// ---------------------------------------------------------------------------
// K1: pillar id + count atomic + arrival rank (NO xyz-sum atomics anymore)
// ---------------------------------------------------------------------------
__global__ __launch_bounds__(256) void k_stats(const float* __restrict__ pts,
                                               unsigned int* __restrict__ cnt,
                                               int* __restrict__ vids,
                                               unsigned int* __restrict__ rank) {
    int tid = blockIdx.x * 256 + threadIdx.x;
    if (tid >= NB * NPT) return;
    const float* p = pts + (size_t)tid * 3;
    float x = p[0], y = p[1];
    // EXACT reference arithmetic: floor((x - lo)/vs), IEEE fp32 divide
    int xi = (int)floorf((x - (-51.2f)) / 0.2f);
    int yi = (int)floorf((y - (-51.2f)) / 0.2f);
    xi = min(max(xi, 0), 511);
    yi = min(max(yi, 0), 511);
    int b = (tid >= NPT) ? 1 : 0;
    int gvid = b * NSEG + (yi * NXg + xi);
    vids[tid] = gvid;
    rank[tid] = atomicAdd(&cnt[gvid], 1u);
}

// ---------------------------------------------------------------------------
// Exclusive prefix scan of cnt[524288] -> offs.  1024 elems/block, 512 blocks.
// ---------------------------------------------------------------------------
__global__ __launch_bounds__(256) void k_scan1(const unsigned int* __restrict__ cnt,
                                               unsigned int* __restrict__ offs,
                                               unsigned int* __restrict__ bsum) {
    __shared__ unsigned int s[256];
    int t = threadIdx.x;
    size_t base = (size_t)blockIdx.x * 1024 + t * 4;
    uint4 c4 = *(const uint4*)(cnt + base);
    unsigned int tsum = c4.x + c4.y + c4.z + c4.w;
    s[t] = tsum;
    __syncthreads();
    for (int o = 1; o < 256; o <<= 1) {
        unsigned int v = (t >= o) ? s[t - o] : 0u;
        __syncthreads();
        s[t] += v;
        __syncthreads();
    }
    unsigned int pre = s[t] - tsum;          // exclusive within block
    if (t == 255) bsum[blockIdx.x] = s[255];
    uint4 o4;
    o4.x = pre; o4.y = pre + c4.x; o4.z = o4.y + c4.y; o4.w = o4.z + c4.z;
    *(uint4*)(offs + base) = o4;
}

__global__ __launch_bounds__(256) void k_scan2(unsigned int* __restrict__ bsum) {
    __shared__ unsigned int s[256];
    int t = threadIdx.x;
    unsigned int a = bsum[2 * t], b = bsum[2 * t + 1];
    unsigned int ts = a + b;
    s[t] = ts;
    __syncthreads();
    for (int o = 1; o < 256; o <<= 1) {
        unsigned int v = (t >= o) ? s[t - o] : 0u;
        __syncthreads();
        s[t] += v;
        __syncthreads();
    }
    unsigned int pre = s[t] - ts;
    bsum[2 * t] = pre;
    bsum[2 * t + 1] = pre + a;
}

__global__ __launch_bounds__(256) void k_scan3(unsigned int* __restrict__ offs,
                                               const unsigned int* __restrict__ bsum) {
    size_t base = (size_t)blockIdx.x * 1024 + threadIdx.x * 4;
    unsigned int add = bsum[blockIdx.x];
    uint4 o4 = *(uint4*)(offs + base);
    o4.x += add; o4.y += add; o4.z += add; o4.w += add;
    *(uint4*)(offs + base) = o4;
}

// ---------------------------------------------------------------------------
// K2: reorder points into pillar-sorted positions (counting sort apply)
// ---------------------------------------------------------------------------
__global__ __launch_bounds__(256) void k_reorder(const float* __restrict__ pts,
                                                 const int* __restrict__ vids,
                                                 const unsigned int* __restrict__ rank,
                                                 const unsigned int* __restrict__ offs,
                                                 float4* __restrict__ sxyz,   // [pos] = x,y,z,gvid-bits
                                                 int* __restrict__ posvid,
                                                 int* __restrict__ ptofpos) {
    int tid = blockIdx.x * 256 + threadIdx.x;
    if (tid >= NB * NPT) return;
    const float* p = pts + (size_t)tid * 3;
    int gvid = vids[tid];
    unsigned pos = offs[gvid] + rank[tid];
    sxyz[pos] = make_float4(p[0], p[1], p[2], __int_as_float(gvid));
    posvid[pos] = gvid;
    ptofpos[pos] = tid;
}

// ---------------------------------------------------------------------------
// K-prep: BN-folded transposed bf16 weights WT[c][k] + fp32 bias for layer 1
// ---------------------------------------------------------------------------
__global__ __launch_bounds__(256) void k_prep(const float* __restrict__ w1,
                                              const float* __restrict__ g1,
                                              const float* __restrict__ b1,
                                              const float* __restrict__ m1,
                                              const float* __restrict__ v1,
                                              unsigned short* __restrict__ wtbf,
                                              float* __restrict__ bias1f) {
    int t = threadIdx.x;
    #pragma unroll
    for (int i = 0; i < 16; ++i) {
        int idx = t + i * 256;               // idx = c*64 + k
        int c = idx >> 6, k = idx & 63;
        float al = g1[c] * rsqrtf(v1[c] + 1e-3f);
        wtbf[idx] = f2bf(w1[k * 64 + c] * al);
    }
    if (t < 64) bias1f[t] = b1[t] - m1[t] * (g1[t] * rsqrtf(v1[t] + 1e-3f));
}

// ---------------------------------------------------------------------------
// K3: position-parallel PFN layer0. Pillar mean from contiguous sorted
//     siblings (avg 1.24/pillar). Output: bf16 h0 half of X rows.
// ---------------------------------------------------------------------------
__global__ __launch_bounds__(256) void k_pfn0(const float4* __restrict__ sxyz,
                                              const unsigned int* __restrict__ offs,
                                              const unsigned int* __restrict__ cnt,
                                              const float* __restrict__ w0,
                                              const float* __restrict__ g0,
                                              const float* __restrict__ b0,
                                              const float* __restrict__ m0,
                                              const float* __restrict__ v0,
                                              unsigned short* __restrict__ xbf) {
    __shared__ float w0f[256];   // BN-folded [8][32]
    __shared__ float bias0[32];
    int t = threadIdx.x;
    {
        int c = t & 31;
        float al = g0[c] * rsqrtf(v0[c] + 1e-3f);
        w0f[t] = w0[t] * al;
        if (t < 32) bias0[t] = b0[t] - m0[t] * al;
    }
    __syncthreads();

    int pos = blockIdx.x * 256 + t;
    if (pos >= NB * NPT) return;

    float4 me = sxyz[pos];
    float x = me.x, y = me.y, z = me.z;
    int gvid = __float_as_int(me.w);
    int vid = gvid & (NSEG - 1);
    int xi = vid & (NXg - 1), yi = vid >> 9;

    unsigned off = offs[gvid];
    unsigned n   = cnt[gvid];               // >= 1 (this point exists)
    float sx = 0.f, sy = 0.f, sz = 0.f;
    for (unsigned i = 0; i < n; ++i) {
        float4 q = sxyz[off + i];
        sx += q.x; sy += q.y; sz += q.z;
    }
    float inv = 1.0f / (float)n;
    float mx = sx * inv, my = sy * inv, mz = sz * inv;
    float cx = ((float)xi + 0.5f) * 0.2f + (-51.2f);
    float cy = ((float)yi + 0.5f) * 0.2f + (-51.2f);

    float f[8] = {x, y, z, x - mx, y - my, z - mz, x - cx, y - cy};

    unsigned wv[16];
    #pragma unroll
    for (int c2 = 0; c2 < 16; ++c2) {
        float a0 = bias0[2 * c2], a1 = bias0[2 * c2 + 1];
        #pragma unroll
        for (int k = 0; k < 8; ++k) {
            a0 += f[k] * w0f[k * 32 + 2 * c2];
            a1 += f[k] * w0f[k * 32 + 2 * c2 + 1];
        }
        unsigned lo = f2bf(fmaxf(a0, 0.0f));
        unsigned hi = f2bf(fmaxf(a1, 0.0f));
        wv[c2] = lo | (hi << 16);
    }
    uint4* dst = (uint4*)(xbf + (size_t)pos * 64);
    dst[0] = make_uint4(wv[0], wv[1], wv[2], wv[3]);
    dst[1] = make_uint4(wv[4], wv[5], wv[6], wv[7]);
    dst[2] = make_uint4(wv[8], wv[9], wv[10], wv[11]);
    dst[3] = make_uint4(wv[12], wv[13], wv[14], wv[15]);
}

// ---------------------------------------------------------------------------
// K4 (fused MFMA): 64 pillars / 256-thread block (4 waves).
//   A : pooled0 max in LDS (bf16 domain, ds atomics, point-parallel)
//   A2: stage X=[h0|pooled] bf16 rows in LDS (XOR-swizzled vs 128B rows)
//   B : per wave 16 points x 64 ch via 8x mfma_f32_16x16x32_bf16,
//       weights in VGPR B-frags; epilogue -> ptfeat + voxl LDS max
//   C : transposed coalesced canvas write
// ---------------------------------------------------------------------------
__global__ __launch_bounds__(256) void k_pfn1(const unsigned short* __restrict__ xbf,
                                              const int* __restrict__ posvid,
                                              const int* __restrict__ ptofpos,
                                              const unsigned int* __restrict__ offs,
                                              const unsigned int* __restrict__ cnt,
                                              const unsigned short* __restrict__ wtbf,
                                              const float* __restrict__ bias1f,
                                              float* __restrict__ ptfeat,
                                              float* __restrict__ canvas) {
    __shared__ unsigned pooled[64][32];      // fp32 bits of bf16 values
    __shared__ unsigned short xlds[64 * 64]; // swizzled bf16 X rows (8KB)
    __shared__ unsigned voxl[64][65];        // fp32 bits, padded
    __shared__ int origarr[64];
    __shared__ unsigned char vlocarr[64];

    int t = threadIdx.x;
    int l = t & 63;                          // lane in wave
    int w = t >> 6;                          // wave 0..3

    int batch = blockIdx.x >> 12;            // 4096 blocks per batch
    int vid0 = (blockIdx.x & 4095) << 6;
    int gvid0 = batch * NSEG + vid0;

    for (int i = t; i < 64 * 32; i += 256) ((unsigned*)pooled)[i] = 0u;
    for (int i = t; i < 64 * 65; i += 256) ((unsigned*)voxl)[i] = 0u;

    unsigned poslo = offs[gvid0];
    unsigned poshi = offs[gvid0 + 63] + cnt[gvid0 + 63];

    // B-fragments: lane holds WT[c = n*16 + l%16][k = ks*32 + (l/16)*8 + e]
    bf16x8 bfr[4][2];
    float bia[4];
    #pragma unroll
    for (int n = 0; n < 4; ++n) {
        #pragma unroll
        for (int ks = 0; ks < 2; ++ks)
            bfr[n][ks] = *(const bf16x8*)(wtbf + ((n * 16 + (l & 15)) * 64 +
                                                  ks * 32 + (l >> 4) * 8));
        bia[n] = bias1f[n * 16 + (l & 15)];
    }
    __syncthreads();

    // ---- Phase A: pooled bf16 max, point-parallel (8 pts/round) ----
    {
        int k = t & 31, g = t >> 5;
        for (unsigned p = poslo + g; p < poshi; p += 8) {
            int vloc = (posvid[p] & (NSEG - 1)) - vid0;
            unsigned u = xbf[(size_t)p * 64 + k];
            atomicMax(&pooled[vloc][k], u << 16);
        }
    }
    __syncthreads();

    // ---- chunks of up to 64 points ----
    for (unsigned pc = poslo; pc < poshi; pc += 64) {
        unsigned m = min(64u, poshi - pc);

        // A2: stage swizzled X rows (zeros beyond m)
        for (int idx = t; idx < 512; idx += 256) {
            int pt = idx >> 3, seg = idx & 7;
            unsigned lin = (unsigned)(pt * 128 + seg * 16);
            unsigned swz = lin ^ ((unsigned)(pt & 7) << 4);
            bf16x8 val;
            #pragma unroll
            for (int e = 0; e < 8; ++e) val[e] = 0;
            if (pt < (int)m) {
                unsigned p = pc + pt;
                if (seg < 4) {
                    val = *(const bf16x8*)(xbf + (size_t)p * 64 + seg * 8);
                } else {
                    int vloc = (posvid[p] & (NSEG - 1)) - vid0;
                    #pragma unroll
                    for (int e = 0; e < 8; ++e)
                        val[e] = (short)(pooled[vloc][(seg - 4) * 8 + e] >> 16);
                    if (seg == 4) {
                        vlocarr[pt] = (unsigned char)vloc;
                        origarr[pt] = ptofpos[p];
                    }
                }
            }
            *(bf16x8*)((char*)xlds + swz) = val;
        }
        __syncthreads();

        // B: MFMA 16 points x 64 channels per wave
        {
            int row = w * 16 + (l & 15);
            unsigned base = (unsigned)(row * 128 + ((l >> 4) << 4));
            unsigned sw = (unsigned)(row & 7) << 4;
            bf16x8 a0 = *(const bf16x8*)((char*)xlds + ((base + 0) ^ sw));
            bf16x8 a1 = *(const bf16x8*)((char*)xlds + ((base + 64) ^ sw));
            #pragma unroll
            for (int n = 0; n < 4; ++n) {
                f32x4 acc = {0.f, 0.f, 0.f, 0.f};
                acc = __builtin_amdgcn_mfma_f32_16x16x32_bf16(a0, bfr[n][0], acc, 0, 0, 0);
                acc = __builtin_amdgcn_mfma_f32_16x16x32_bf16(a1, bfr[n][1], acc, 0, 0, 0);
                int ch = n * 16 + (l & 15);
                #pragma unroll
                for (int r = 0; r < 4; ++r) {
                    int pidx = w * 16 + (l >> 4) * 4 + r;   // C: row=(l>>4)*4+r
                    float v = fmaxf(acc[r] + bia[n], 0.0f);
                    if (pidx < (int)m) {
                        ptfeat[(size_t)origarr[pidx] * 64 + ch] = v;
                        atomicMax(&voxl[vlocarr[pidx]][ch], __float_as_uint(v));
                    }
                }
            }
        }
        __syncthreads();
    }

    // ---- Phase C: transposed canvas write ----
    {
        float* cv = canvas + (size_t)batch * 64 * NSEG + vid0;
        int p = l;
        #pragma unroll
        for (int i = 0; i < 16; ++i) {
            int c = i * 4 + w;
            cv[(size_t)c * NSEG + p] = __uint_as_float(voxl[p][c]);
        }
    }
}

// ---------------------------------------------------------------------------
extern "C" void kernel_launch(void* const* d_in, const int* in_sizes, int n_in,
                              void* d_out, int out_size, void* d_ws, size_t ws_size,
                              hipStream_t stream) {
    const float* pts = (const float*)d_in[0];
    const float* w0  = (const float*)d_in[1];
    const float* g0  = (const float*)d_in[2];
    const float* b0  = (const float*)d_in[3];
    const float* m0  = (const float*)d_in[4];
    const float* v0  = (const float*)d_in[5];
    const float* w1  = (const float*)d_in[6];
    const float* g1  = (const float*)d_in[7];
    const float* b1  = (const float*)d_in[8];
    const float* m1  = (const float*)d_in[9];
    const float* v1  = (const float*)d_in[10];
    float* out = (float*)d_out;
    float* ptfeat = out + (size_t)NB * 64 * NSEG;   // point_feats after canvases

    // workspace layout (~43 MB)
    char* ws = (char*)d_ws;
    size_t off = 0;
    unsigned int* cnt   = (unsigned int*)(ws + off); off += (size_t)NSEGT * 4;
    unsigned int* offs  = (unsigned int*)(ws + off); off += (size_t)NSEGT * 4;
    int* vids           = (int*)(ws + off);          off += (size_t)NB * NPT * 4;
    unsigned int* rank  = (unsigned int*)(ws + off); off += (size_t)NB * NPT * 4;
    int* posvid         = (int*)(ws + off);          off += (size_t)NB * NPT * 4;
    int* ptofpos        = (int*)(ws + off);          off += (size_t)NB * NPT * 4;
    float4* sxyz        = (float4*)(ws + off);       off += (size_t)NB * NPT * 16;
    unsigned short* xbf = (unsigned short*)(ws + off); off += (size_t)NB * NPT * 64 * 2;
    unsigned short* wtbf= (unsigned short*)(ws + off); off += 4096 * 2;
    float* bias1f       = (float*)(ws + off);        off += 64 * 4;
    unsigned int* bsum  = (unsigned int*)(ws + off); off += 512 * 4;

    hipMemsetAsync(cnt, 0, (size_t)NSEGT * 4, stream);

    int npts = NB * NPT;
    int nblk = (npts + 255) / 256;
    k_stats<<<nblk, 256, 0, stream>>>(pts, cnt, vids, rank);
    k_scan1<<<NSEGT / 1024, 256, 0, stream>>>(cnt, offs, bsum);
    k_scan2<<<1, 256, 0, stream>>>(bsum);
    k_scan3<<<NSEGT / 1024, 256, 0, stream>>>(offs, bsum);
    k_reorder<<<nblk, 256, 0, stream>>>(pts, vids, rank, offs, sxyz, posvid, ptofpos);
    k_prep<<<1, 256, 0, stream>>>(w1, g1, b1, m1, v1, wtbf, bias1f);
    k_pfn0<<<nblk, 256, 0, stream>>>(sxyz, offs, cnt, w0, g0, b0, m0, v0, xbf);
    k_pfn1<<<NB * 4096, 256, 0, stream>>>(xbf, posvid, ptofpos, offs, cnt,
                                          wtbf, bias1f, ptfeat, out);
}

// Round 7
// 129.045 us; speedup vs baseline: 7.5800x; 1.0030x over previous
//
#include <hip/hip_runtime.h>

#define NPT   120000            // points per batch
#define NB    2                 // batches
#define NSEG  262144            // 512*512 pillars
#define NXg   512
#define NSEGT (NB * NSEG)       // 524288 total segments
#define NPTS  (NB * NPT)        // 240000 total points

typedef __attribute__((ext_vector_type(8))) short  bf16x8;
typedef __attribute__((ext_vector_type(4))) float  f32x4;

__device__ __forceinline__ unsigned short f2bf(float f) {
    unsigned u = __float_as_uint(f);
    return (unsigned short)((u + 0x7FFFu + ((u >> 16) & 1u)) >> 16);   // RNE
}

// ---------------------------------------------------------------------------
// K0: zero cnt (custom fill — hipMemsetAsync's rocclr fill ran at 18 GB/s)
//     + BN-fold layer-1 weights (transposed bf16) in the extra block.
// ---------------------------------------------------------------------------
__global__ __launch_bounds__(256) void k_init(unsigned int* __restrict__ cnt,
                                              const float* __restrict__ w1,
                                              const float* __restrict__ g1,
                                              const float* __restrict__ b1,
                                              const float* __restrict__ m1,
                                              const float* __restrict__ v1,
                                              unsigned short* __restrict__ wtbf,
                                              float* __restrict__ bias1f) {
    int t = threadIdx.x;
    if (blockIdx.x < 512) {
        int idx = blockIdx.x * 256 + t;          // 131072 uint4 = 2 MB
        ((uint4*)cnt)[idx] = make_uint4(0u, 0u, 0u, 0u);
        return;
    }
    // prep block
    #pragma unroll
    for (int i = 0; i < 16; ++i) {
        int idx = t + i * 256;                   // idx = c*64 + k
        int c = idx >> 6, k = idx & 63;
        float al = g1[c] * rsqrtf(v1[c] + 1e-3f);
        wtbf[idx] = f2bf(w1[k * 64 + c] * al);
    }
    if (t < 64) bias1f[t] = b1[t] - m1[t] * (g1[t] * rsqrtf(v1[t] + 1e-3f));
}

// ---------------------------------------------------------------------------
// K1: pillar id -> count atomic + arrival rank
// ---------------------------------------------------------------------------
__global__ __launch_bounds__(256) void k_stats(const float* __restrict__ pts,
                                               unsigned int* __restrict__ cnt,
                                               unsigned int* __restrict__ rank) {
    int tid = blockIdx.x * 256 + threadIdx.x;
    if (tid >= NPTS) return;
    const float* p = pts + (size_t)tid * 3;
    float x = p[0], y = p[1];
    // EXACT reference arithmetic: floor((x - lo)/vs), IEEE fp32 divide
    int xi = (int)floorf((x - (-51.2f)) / 0.2f);
    int yi = (int)floorf((y - (-51.2f)) / 0.2f);
    xi = min(max(xi, 0), 511);
    yi = min(max(yi, 0), 511);
    int b = (tid >= NPT) ? 1 : 0;
    int gvid = b * NSEG + (yi * NXg + xi);
    rank[tid] = atomicAdd(&cnt[gvid], 1u);
}

// ---------------------------------------------------------------------------
// Prefix scan of cnt[524288]: block-local offs + bsum, then scan bsum.
// Consumers add bsum[g>>10] (scan3 eliminated).
// ---------------------------------------------------------------------------
__global__ __launch_bounds__(256) void k_scan1(const unsigned int* __restrict__ cnt,
                                               unsigned int* __restrict__ offs,
                                               unsigned int* __restrict__ bsum) {
    __shared__ unsigned int s[256];
    int t = threadIdx.x;
    size_t base = (size_t)blockIdx.x * 1024 + t * 4;
    uint4 c4 = *(const uint4*)(cnt + base);
    unsigned int tsum = c4.x + c4.y + c4.z + c4.w;
    s[t] = tsum;
    __syncthreads();
    for (int o = 1; o < 256; o <<= 1) {
        unsigned int v = (t >= o) ? s[t - o] : 0u;
        __syncthreads();
        s[t] += v;
        __syncthreads();
    }
    unsigned int pre = s[t] - tsum;          // exclusive within block
    if (t == 255) bsum[blockIdx.x] = s[255];
    uint4 o4;
    o4.x = pre; o4.y = pre + c4.x; o4.z = o4.y + c4.y; o4.w = o4.z + c4.z;
    *(uint4*)(offs + base) = o4;
}

__global__ __launch_bounds__(256) void k_scan2(unsigned int* __restrict__ bsum) {
    __shared__ unsigned int s[256];
    int t = threadIdx.x;
    unsigned int a = bsum[2 * t], b = bsum[2 * t + 1];
    unsigned int ts = a + b;
    s[t] = ts;
    __syncthreads();
    for (int o = 1; o < 256; o <<= 1) {
        unsigned int v = (t >= o) ? s[t - o] : 0u;
        __syncthreads();
        s[t] += v;
        __syncthreads();
    }
    unsigned int pre = s[t] - ts;
    bsum[2 * t] = pre;
    bsum[2 * t + 1] = pre + a;
}

// ---------------------------------------------------------------------------
// K2: counting-sort apply. pos = offs[gvid] + bsum[g>>10] + rank.
//     comb packs (vid&63)<<18 | tid  (tid < 2^18).
// ---------------------------------------------------------------------------
__global__ __launch_bounds__(256) void k_reorder(const float* __restrict__ pts,
                                                 const unsigned int* __restrict__ rank,
                                                 const unsigned int* __restrict__ offs,
                                                 const unsigned int* __restrict__ bsum,
                                                 float4* __restrict__ sxyz,
                                                 unsigned int* __restrict__ comb) {
    int tid = blockIdx.x * 256 + threadIdx.x;
    if (tid >= NPTS) return;
    const float* p = pts + (size_t)tid * 3;
    float x = p[0], y = p[1], z = p[2];
    int xi = (int)floorf((x - (-51.2f)) / 0.2f);
    int yi = (int)floorf((y - (-51.2f)) / 0.2f);
    xi = min(max(xi, 0), 511);
    yi = min(max(yi, 0), 511);
    int b = (tid >= NPT) ? 1 : 0;
    int gvid = b * NSEG + (yi * NXg + xi);
    unsigned pos = offs[gvid] + bsum[gvid >> 10] + rank[tid];
    sxyz[pos] = make_float4(x, y, z, __int_as_float(gvid));
    comb[pos] = ((unsigned)(gvid & 63) << 18) | (unsigned)tid;
}

// ---------------------------------------------------------------------------
// K3: PFN layer0, position-parallel. Computes pillar mean AND pillar pooled
//     max by recomputing sibling h0 (siblings contiguous, avg 1.46/point).
//     Writes the complete 128B bf16 X-row [h0 | pooled]  (8 uint4!).
// ---------------------------------------------------------------------------
__global__ __launch_bounds__(256) void k_pfn0(const float4* __restrict__ sxyz,
                                              const unsigned int* __restrict__ offs,
                                              const unsigned int* __restrict__ bsum,
                                              const unsigned int* __restrict__ cnt,
                                              const float* __restrict__ w0,
                                              const float* __restrict__ g0,
                                              const float* __restrict__ b0,
                                              const float* __restrict__ m0,
                                              const float* __restrict__ v0,
                                              unsigned short* __restrict__ xbf) {
    __shared__ float w0f[256];   // BN-folded [8][32]
    __shared__ float bias0[32];
    int t = threadIdx.x;
    {
        int c = t & 31;
        float al = g0[c] * rsqrtf(v0[c] + 1e-3f);
        w0f[t] = w0[t] * al;
        if (t < 32) bias0[t] = b0[t] - m0[t] * al;
    }
    __syncthreads();

    int pos = blockIdx.x * 256 + t;
    if (pos >= NPTS) return;

    float4 me = sxyz[pos];
    int gvid = __float_as_int(me.w);
    int vid = gvid & (NSEG - 1);
    int xi = vid & (NXg - 1), yi = vid >> 9;

    unsigned off = offs[gvid] + bsum[gvid >> 10];
    unsigned n   = cnt[gvid];               // >= 1
    float sx = 0.f, sy = 0.f, sz = 0.f;
    for (unsigned i = 0; i < n; ++i) {
        float4 q = sxyz[off + i];
        sx += q.x; sy += q.y; sz += q.z;
    }
    float inv = 1.0f / (float)n;
    float mx = sx * inv, my = sy * inv, mz = sz * inv;
    float cx = ((float)xi + 0.5f) * 0.2f + (-51.2f);
    float cy = ((float)yi + 0.5f) * 0.2f + (-51.2f);

    float own[32], pool[32];
    #pragma unroll
    for (int c = 0; c < 32; ++c) { pool[c] = 0.0f; own[c] = 0.0f; }
    for (unsigned i = 0; i < n; ++i) {
        float4 q = sxyz[off + i];
        float f[8] = {q.x, q.y, q.z, q.x - mx, q.y - my, q.z - mz,
                      q.x - cx, q.y - cy};
        bool self = (off + i == (unsigned)pos);
        #pragma unroll
        for (int c = 0; c < 32; ++c) {
            float acc = bias0[c];
            #pragma unroll
            for (int k = 0; k < 8; ++k) acc += f[k] * w0f[k * 32 + c];
            acc = fmaxf(acc, 0.0f);
            pool[c] = fmaxf(pool[c], acc);
            if (self) own[c] = acc;
        }
    }

    // full 128B row: own -> dst[0..3], pool -> dst[4..7]
    unsigned wv[16];
    uint4* dst = (uint4*)(xbf + (size_t)pos * 64);
    #pragma unroll
    for (int c2 = 0; c2 < 16; ++c2)
        wv[c2] = (unsigned)f2bf(own[2 * c2]) | ((unsigned)f2bf(own[2 * c2 + 1]) << 16);
    dst[0] = make_uint4(wv[0],  wv[1],  wv[2],  wv[3]);
    dst[1] = make_uint4(wv[4],  wv[5],  wv[6],  wv[7]);
    dst[2] = make_uint4(wv[8],  wv[9],  wv[10], wv[11]);
    dst[3] = make_uint4(wv[12], wv[13], wv[14], wv[15]);
    #pragma unroll
    for (int c2 = 0; c2 < 16; ++c2)
        wv[c2] = (unsigned)f2bf(pool[2 * c2]) | ((unsigned)f2bf(pool[2 * c2 + 1]) << 16);
    dst[4] = make_uint4(wv[0],  wv[1],  wv[2],  wv[3]);
    dst[5] = make_uint4(wv[4],  wv[5],  wv[6],  wv[7]);
    dst[6] = make_uint4(wv[8],  wv[9],  wv[10], wv[11]);
    dst[7] = make_uint4(wv[12], wv[13], wv[14], wv[15]);
}

// ---------------------------------------------------------------------------
// K4 (fused MFMA): 64 pillars / 256-thread block (4 waves).
//   stage: linear coalesced copy of complete X rows (XOR-swizzled LDS)
//   B    : 16 points x 64 ch per wave via 8x mfma_f32_16x16x32_bf16
//   C    : transposed coalesced canvas write
// ---------------------------------------------------------------------------
__global__ __launch_bounds__(256) void k_pfn1(const unsigned short* __restrict__ xbf,
                                              const unsigned int* __restrict__ comb,
                                              const unsigned int* __restrict__ offs,
                                              const unsigned int* __restrict__ bsum,
                                              const unsigned short* __restrict__ wtbf,
                                              const float* __restrict__ bias1f,
                                              float* __restrict__ ptfeat,
                                              float* __restrict__ canvas) {
    __shared__ unsigned short xlds[64 * 64]; // swizzled bf16 X rows (8KB)
    __shared__ unsigned voxl[64][65];        // fp32 bits, padded
    __shared__ unsigned combs[64];

    int t = threadIdx.x;
    int l = t & 63;                          // lane in wave
    int w = t >> 6;                          // wave 0..3

    int batch = blockIdx.x >> 12;            // 4096 blocks per batch
    int vid0 = (blockIdx.x & 4095) << 6;
    int gvid0 = batch * NSEG + vid0;

    #pragma unroll
    for (int i = 0; i < 17; ++i) {
        int idx = t + i * 256;
        if (idx < 64 * 65) ((unsigned*)voxl)[idx] = 0u;
    }

    unsigned poslo = offs[gvid0] + bsum[gvid0 >> 10];
    int g2 = gvid0 + 64;
    unsigned poshi = (g2 < NSEGT) ? offs[g2] + bsum[g2 >> 10] : (unsigned)NPTS;

    // B-fragments: lane holds WT[c = n*16 + l%16][k = ks*32 + (l/16)*8 + e]
    bf16x8 bfr[4][2];
    float bia[4];
    #pragma unroll
    for (int n = 0; n < 4; ++n) {
        #pragma unroll
        for (int ks = 0; ks < 2; ++ks)
            bfr[n][ks] = *(const bf16x8*)(wtbf + ((n * 16 + (l & 15)) * 64 +
                                                  ks * 32 + (l >> 4) * 8));
        bia[n] = bias1f[n * 16 + (l & 15)];
    }
    __syncthreads();                         // voxl init visible (empty-tile path)

    for (unsigned pc = poslo; pc < poshi; pc += 64) {
        unsigned m = min(64u, poshi - pc);

        // stage: linear coalesced read of 128B rows, swizzled LDS write
        for (int idx = t; idx < 512; idx += 256) {
            int pt = idx >> 3, seg = idx & 7;
            unsigned lin = (unsigned)(pt * 128 + seg * 16);
            unsigned swz = lin ^ ((unsigned)(pt & 7) << 4);
            bf16x8 val;
            #pragma unroll
            for (int e = 0; e < 8; ++e) val[e] = 0;
            if (pt < (int)m)
                val = *(const bf16x8*)(xbf + (size_t)(pc + pt) * 64 + seg * 8);
            *(bf16x8*)((char*)xlds + swz) = val;
        }
        for (int pt = t; pt < (int)m; pt += 256) combs[pt] = comb[pc + pt];
        __syncthreads();

        // MFMA: 16 points x 64 channels per wave
        {
            int row = w * 16 + (l & 15);
            unsigned base = (unsigned)(row * 128 + ((l >> 4) << 4));
            unsigned sw = (unsigned)(row & 7) << 4;
            bf16x8 a0 = *(const bf16x8*)((char*)xlds + ((base + 0) ^ sw));
            bf16x8 a1 = *(const bf16x8*)((char*)xlds + ((base + 64) ^ sw));
            #pragma unroll
            for (int n = 0; n < 4; ++n) {
                f32x4 acc = {0.f, 0.f, 0.f, 0.f};
                acc = __builtin_amdgcn_mfma_f32_16x16x32_bf16(a0, bfr[n][0], acc, 0, 0, 0);
                acc = __builtin_amdgcn_mfma_f32_16x16x32_bf16(a1, bfr[n][1], acc, 0, 0, 0);
                int ch = n * 16 + (l & 15);
                #pragma unroll
                for (int r = 0; r < 4; ++r) {
                    int pidx = w * 16 + (l >> 4) * 4 + r;   // C: row=(l>>4)*4+r
                    if (pidx < (int)m) {
                        unsigned u = combs[pidx];
                        float v = fmaxf(acc[r] + bia[n], 0.0f);
                        ptfeat[(size_t)(u & 0x3FFFFu) * 64 + ch] = v;
                        atomicMax(&voxl[u >> 18][ch], __float_as_uint(v));
                    }
                }
            }
        }
        __syncthreads();
    }

    // transposed canvas write
    {
        float* cv = canvas + (size_t)batch * 64 * NSEG + vid0;
        #pragma unroll
        for (int i = 0; i < 16; ++i) {
            int c = i * 4 + w;
            cv[(size_t)c * NSEG + l] = __uint_as_float(voxl[l][c]);
        }
    }
}

// ---------------------------------------------------------------------------
extern "C" void kernel_launch(void* const* d_in, const int* in_sizes, int n_in,
                              void* d_out, int out_size, void* d_ws, size_t ws_size,
                              hipStream_t stream) {
    const float* pts = (const float*)d_in[0];
    const float* w0  = (const float*)d_in[1];
    const float* g0  = (const float*)d_in[2];
    const float* b0  = (const float*)d_in[3];
    const float* m0  = (const float*)d_in[4];
    const float* v0  = (const float*)d_in[5];
    const float* w1  = (const float*)d_in[6];
    const float* g1  = (const float*)d_in[7];
    const float* b1  = (const float*)d_in[8];
    const float* m1  = (const float*)d_in[9];
    const float* v1  = (const float*)d_in[10];
    float* out = (float*)d_out;
    float* ptfeat = out + (size_t)NB * 64 * NSEG;   // point_feats after canvases

    // workspace layout (~41 MB)
    char* ws = (char*)d_ws;
    size_t off = 0;
    unsigned int* cnt   = (unsigned int*)(ws + off); off += (size_t)NSEGT * 4;
    unsigned int* offs  = (unsigned int*)(ws + off); off += (size_t)NSEGT * 4;
    unsigned int* rank  = (unsigned int*)(ws + off); off += (size_t)NPTS * 4;
    unsigned int* comb  = (unsigned int*)(ws + off); off += (size_t)NPTS * 4;
    float4* sxyz        = (float4*)(ws + off);       off += (size_t)NPTS * 16;
    unsigned short* xbf = (unsigned short*)(ws + off); off += (size_t)NPTS * 64 * 2;
    unsigned short* wtbf= (unsigned short*)(ws + off); off += 4096 * 2;
    float* bias1f       = (float*)(ws + off);        off += 64 * 4;
    unsigned int* bsum  = (unsigned int*)(ws + off); off += 512 * 4;

    int nblk = (NPTS + 255) / 256;
    k_init<<<513, 256, 0, stream>>>(cnt, w1, g1, b1, m1, v1, wtbf, bias1f);
    k_stats<<<nblk, 256, 0, stream>>>(pts, cnt, rank);
    k_scan1<<<NSEGT / 1024, 256, 0, stream>>>(cnt, offs, bsum);
    k_scan2<<<1, 256, 0, stream>>>(bsum);
    k_reorder<<<nblk, 256, 0, stream>>>(pts, rank, offs, bsum, sxyz, comb);
    k_pfn0<<<nblk, 256, 0, stream>>>(sxyz, offs, bsum, cnt,
                                     w0, g0, b0, m0, v0, xbf);
    k_pfn1<<<NB * 4096, 256, 0, stream>>>(xbf, comb, offs, bsum,
                                          wtbf, bias1f, ptfeat, out);
}